// Round 15
// baseline (106.482 us; speedup 1.0000x reference)
//
#include <hip/hip_runtime.h>
#include <hip/hip_bf16.h>

// Problem constants (B=4, S=4096, D=1024 from reference)
#define B_DIM 4
#define S_DIM 4096
#define D_DIM 1024
#define M_TOT (B_DIM * S_DIM)      // 16384 rows of flattened [B*S, D]
#define LOOKBACK 32                 // d^32 ~ 1.8e-5 rel: far below threshold
#define CHUNK 128                   // S-rows produced per scan block
#define NT (D_DIM / 64)             // 16 K-tiles of BK=64

typedef unsigned short us;
typedef __attribute__((ext_vector_type(8))) short bf16x8;   // 8 bf16 (4 VGPRs)
typedef __attribute__((ext_vector_type(4))) float f32x4;    // MFMA accumulator
typedef __attribute__((ext_vector_type(4))) unsigned short u16x4;

__device__ __forceinline__ us f2bf(float f) {
  unsigned int u = __builtin_bit_cast(unsigned int, f);
  u += 0x7fffu + ((u >> 16) & 1u);
  return (us)(u >> 16);
}

// ---------------------------------------------------------------------------
// Kernel 1: chunked parallel EMA scan -> causal bf16 in ws.
// ---------------------------------------------------------------------------
__global__ __launch_bounds__(256) void scan_kernel(
    const float* __restrict__ x, const float* __restrict__ dp,
    us* __restrict__ causal) {
  const float dcy = 1.0f / (1.0f + expf(-dp[0]));
  const float omd = 1.0f - dcy;
  const int d0 = blockIdx.x * 512 + threadIdx.x;
  const int s0 = blockIdx.y * CHUNK;
  const size_t base = (size_t)blockIdx.z * S_DIM * D_DIM + d0;
  float st0 = 0.f, st1 = 0.f;
  if (s0 > 0) {
    const float* px = x + base + (size_t)(s0 - LOOKBACK) * D_DIM;
#pragma unroll 8
    for (int i = 0; i < LOOKBACK; ++i) {
      st0 = dcy * st0 + omd * px[0];
      st1 = dcy * st1 + omd * px[256];
      px += D_DIM;
    }
  }
  const float* px = x + base + (size_t)s0 * D_DIM;
  us* pc = causal + base + (size_t)s0 * D_DIM;
#pragma unroll 8
  for (int i = 0; i < CHUNK; ++i) {
    st0 = dcy * st0 + omd * px[0];
    st1 = dcy * st1 + omd * px[256];
    pc[0]   = f2bf(st0);
    pc[256] = f2bf(st1);
    px += D_DIM;
    pc += D_DIM;
  }
}

// ---------------------------------------------------------------------------
// Kernel 2: W fp32 -> bf16
// ---------------------------------------------------------------------------
__global__ __launch_bounds__(256) void convw_kernel(
    const float* __restrict__ W, us* __restrict__ Wb) {
  const int i = (blockIdx.x * 256 + threadIdx.x) * 4;
  const float4 v = *(const float4*)(W + i);
  u16x4 o;
  o.x = f2bf(v.x); o.y = f2bf(v.y); o.z = f2bf(v.z); o.w = f2bf(v.w);
  *(u16x4*)(Wb + i) = o;
}

// ---------------------------------------------------------------------------
// Kernel 3: out = x + causal(bf16) @ Wb(bf16)^T — B-DIRECT-FROM-L2 variant.
// Diagnosis: 10 variants pinned at 52+-2 us by the global->LDS->VGPR round
// trip.  W (2 MB bf16) is L2-resident by construction (every block on the
// XCD reads it) -> B fragments now load global->VGPR directly, pingpong-
// buffered (static bP/bQ), prefetched one full K-tile ahead (~500 cy cover
// vs ~200 cy L2 latency).  LDS holds ONLY A (XOR-swizzled dbuf, 32 KB):
// LDS traffic /3, and B's cross-wave hazard vanishes -> ONE barrier/K-tile.
// BM=BN=128, BK=64, 4 waves of 64x64, grid 1024, 2 blocks/CU.
// Per K-tile: {LOAD_B(t+1)->other breg; STAGE_A(t+1)->other Abuf;
//              a-reads(t); 32 MFMA; vmcnt(0); BAR}.
// WAR: A-stage targets p^1 (last read iter t-1, ordered by prior BAR).
// Falsifier watched: FETCH_SIZE >> 100 MB means W fell out of L2 (R11 mode).
// ---------------------------------------------------------------------------
__global__ __launch_bounds__(256, 2) void gemm_kernel(
    const us* __restrict__ A,   // causal bf16 [M_TOT][D_DIM]
    const us* __restrict__ Bw,  // W bf16 [D_DIM][D_DIM]
    const float* __restrict__ x,
    float* __restrict__ out) {
  __shared__ us smem_s[16384];  // 32 KB: A buf p at p*8192 (16 KB each)

  // nwg = 1024 = 8 XCDs x 128; n-major within XCD chunk (A-band + W hot in L2)
  const int bid = blockIdx.x;
  const int xcd = bid & 7;
  const int q = bid >> 3;                   // 0..127
  const int m0 = (xcd * 16 + (q >> 3)) * 128;
  const int n0 = (q & 7) * 128;

  const int tid = threadIdx.x;
  const int lane = tid & 63;
  const int wave = tid >> 6;
  const int wr = wave >> 1;       // 0..1 (M half: 64 rows)
  const int wc = wave & 1;        // 0..1 (N half: 64 cols)
  const int lrow = lane & 15;
  const int ls   = lane >> 4;     // 0..3
  const int koff0 = ((0 + ls) ^ (lane & 7)) * 8;
  const int koff1 = ((4 + ls) ^ (lane & 7)) * 8;
  const int arow = (wr * 64 + lrow) * 64;   // + mi*1024 + koff

  // Per-lane B base: W row = n0 + wc*64 + nj*16 + lrow, k-slot = ls*8 + ks*32
  const us* const pB = Bw + (size_t)(n0 + wc * 64 + lrow) * D_DIM + ls * 8;

  f32x4 acc[4][4];
#pragma unroll
  for (int i = 0; i < 4; ++i)
#pragma unroll
    for (int j = 0; j < 4; ++j) acc[i][j] = (f32x4)0.f;

  // ---- B fragment load: 8 x global bf16x8 (16 rows x 64 B, L2-resident) ----
#define LOAD_B(DST, t)                                                         \
  {                                                                            \
    const us* pt = pB + (t) * 64;                                              \
    _Pragma("unroll")                                                          \
    for (int nj = 0; nj < 4; ++nj) {                                           \
      DST[nj][0] = *(const bf16x8*)(pt + (size_t)nj * 16 * D_DIM);             \
      DST[nj][1] = *(const bf16x8*)(pt + (size_t)nj * 16 * D_DIM + 32);        \
    }                                                                          \
  }

  // ---- A stage: 128x64 bf16 = 16 KB = 1024 chunks, 4 gload_lds/thread ----
#define STAGE_A(t, ldsbase)                                                    \
  {                                                                            \
    _Pragma("unroll")                                                          \
    for (int it = 0; it < 4; ++it) {                                           \
      const int c = it * 256 + tid;          /* 0..1023 */                     \
      const int r = c >> 3;                  /* 0..127  */                     \
      const int slot = (c & 7) ^ (r & 7);                                      \
      __builtin_amdgcn_global_load_lds(                                        \
          (const __attribute__((address_space(1))) void*)(A +                  \
              (size_t)(m0 + r) * D_DIM + (t) * 64 + slot * 8),                 \
          (__attribute__((address_space(3))) void*)(smem_s + (ldsbase) + c * 8),\
          16, 0, 0);                                                           \
    }                                                                          \
  }

  // ---- one K-tile: a-reads from LDS + 32 MFMA against B regs ----
#define COMPUTE(ABASE, BF)                                                     \
  {                                                                            \
    bf16x8 a[4][2];                                                            \
    _Pragma("unroll")                                                          \
    for (int mi = 0; mi < 4; ++mi) {                                           \
      a[mi][0] = *(const bf16x8*)(smem_s + (ABASE) + arow + mi * 1024 + koff0);\
      a[mi][1] = *(const bf16x8*)(smem_s + (ABASE) + arow + mi * 1024 + koff1);\
    }                                                                          \
    __builtin_amdgcn_s_setprio(1);                                             \
    _Pragma("unroll")                                                          \
    for (int ks = 0; ks < 2; ++ks)                                             \
      _Pragma("unroll")                                                        \
      for (int mi = 0; mi < 4; ++mi)                                           \
        _Pragma("unroll")                                                      \
        for (int nj = 0; nj < 4; ++nj)                                         \
          acc[mi][nj] = __builtin_amdgcn_mfma_f32_16x16x32_bf16(               \
              a[mi][ks], BF[nj][ks], acc[mi][nj], 0, 0, 0);                    \
    __builtin_amdgcn_s_setprio(0);                                             \
  }
#define DRAIN_BAR()                                                            \
  asm volatile("s_waitcnt vmcnt(0)" ::: "memory");                             \
  __builtin_amdgcn_s_barrier()

  bf16x8 bP[4][2], bQ[4][2];

  // ---- prologue: A(0) -> buf0, B(0) -> bP ----
  STAGE_A(0, 0);
  LOAD_B(bP, 0);
  DRAIN_BAR();

  // ---- main loop, unrolled by 2 for static bP/bQ pingpong ----
  for (int tt = 0; tt < NT; tt += 2) {
    if (tt + 1 < NT) { LOAD_B(bQ, tt + 1); STAGE_A(tt + 1, 8192); }
    COMPUTE(0, bP);
    DRAIN_BAR();
    if (tt + 2 < NT) { LOAD_B(bP, tt + 2); STAGE_A(tt + 2, 0); }
    COMPUTE(8192, bQ);
    DRAIN_BAR();
  }

  // ---- epilogue: out = x + acc.  C/D: col = lane&15, row = (lane>>4)*4+r ----
#pragma unroll
  for (int mi = 0; mi < 4; ++mi)
#pragma unroll
    for (int nj = 0; nj < 4; ++nj) {
      const int ocol = n0 + wc * 64 + nj * 16 + lrow;
      const int orow0 = m0 + wr * 64 + mi * 16 + ls * 4;
#pragma unroll
      for (int r = 0; r < 4; ++r) {
        const size_t idx = (size_t)(orow0 + r) * D_DIM + ocol;
        out[idx] = x[idx] + acc[mi][nj][r];
      }
    }
#undef LOAD_B
#undef STAGE_A
#undef COMPUTE
#undef DRAIN_BAR
}

extern "C" void kernel_launch(void* const* d_in, const int* in_sizes, int n_in,
                              void* d_out, int out_size, void* d_ws, size_t ws_size,
                              hipStream_t stream) {
  const float* x  = (const float*)d_in[0];
  const float* dp = (const float*)d_in[1];
  const float* W  = (const float*)d_in[2];
  float* out = (float*)d_out;

  us* causal = (us*)d_ws;
  us* Wb = (us*)((char*)d_ws + (size_t)M_TOT * D_DIM * 2);

  dim3 g_scan(D_DIM / 512, S_DIM / CHUNK, B_DIM);
  scan_kernel<<<g_scan, 256, 0, stream>>>(x, dp, causal);

  convw_kernel<<<(D_DIM * D_DIM) / (256 * 4), 256, 0, stream>>>(W, Wb);

  gemm_kernel<<<(M_TOT / 128) * (D_DIM / 128), 256, 0, stream>>>(
      causal, Wb, x, out);
}

// Round 16
// 67.378 us; speedup vs baseline: 1.5804x; 1.5804x over previous
//
#include <hip/hip_runtime.h>
#include <hip/hip_bf16.h>

// Problem constants (B=4, S=4096, D=1024 from reference)
#define B_DIM 4
#define S_DIM 4096
#define D_DIM 1024
#define M_TOT (B_DIM * S_DIM)      // 16384 rows of flattened [B*S, D]
#define LOOKBACK 32                 // d^32 ~ 1.8e-5 rel: far below threshold
#define CHUNK 128                   // S-rows produced per scan block
#define NT (D_DIM / 64)             // 16 K-tiles of BK=64

typedef unsigned short us;
typedef __attribute__((ext_vector_type(8))) short bf16x8;   // 8 bf16 (4 VGPRs)
typedef __attribute__((ext_vector_type(4))) float f32x4;    // MFMA accumulator
typedef __attribute__((ext_vector_type(4))) unsigned short u16x4;

__device__ __forceinline__ us f2bf(float f) {
  unsigned int u = __builtin_bit_cast(unsigned int, f);
  u += 0x7fffu + ((u >> 16) & 1u);
  return (us)(u >> 16);
}

// ---------------------------------------------------------------------------
// Kernel 1: chunked parallel EMA scan -> causal bf16 in ws.
// ---------------------------------------------------------------------------
__global__ __launch_bounds__(256) void scan_kernel(
    const float* __restrict__ x, const float* __restrict__ dp,
    us* __restrict__ causal) {
  const float dcy = 1.0f / (1.0f + expf(-dp[0]));
  const float omd = 1.0f - dcy;
  const int d0 = blockIdx.x * 512 + threadIdx.x;
  const int s0 = blockIdx.y * CHUNK;
  const size_t base = (size_t)blockIdx.z * S_DIM * D_DIM + d0;
  float st0 = 0.f, st1 = 0.f;
  if (s0 > 0) {
    const float* px = x + base + (size_t)(s0 - LOOKBACK) * D_DIM;
#pragma unroll 8
    for (int i = 0; i < LOOKBACK; ++i) {
      st0 = dcy * st0 + omd * px[0];
      st1 = dcy * st1 + omd * px[256];
      px += D_DIM;
    }
  }
  const float* px = x + base + (size_t)s0 * D_DIM;
  us* pc = causal + base + (size_t)s0 * D_DIM;
#pragma unroll 8
  for (int i = 0; i < CHUNK; ++i) {
    st0 = dcy * st0 + omd * px[0];
    st1 = dcy * st1 + omd * px[256];
    pc[0]   = f2bf(st0);
    pc[256] = f2bf(st1);
    px += D_DIM;
    pc += D_DIM;
  }
}

// ---------------------------------------------------------------------------
// Kernel 2: W fp32 -> bf16
// ---------------------------------------------------------------------------
__global__ __launch_bounds__(256) void convw_kernel(
    const float* __restrict__ W, us* __restrict__ Wb) {
  const int i = (blockIdx.x * 256 + threadIdx.x) * 4;
  const float4 v = *(const float4*)(W + i);
  u16x4 o;
  o.x = f2bf(v.x); o.y = f2bf(v.y); o.z = f2bf(v.z); o.w = f2bf(v.w);
  *(u16x4*)(Wb + i) = o;
}

// ---------------------------------------------------------------------------
// Kernel 3: out = x + causal(bf16) @ Wb(bf16)^T  — R8 geometry, DEEP STAGING.
// 128x128 tile, BK=64, 512 thr = 8 waves (2Mx4N, 64x32/wave), 64 KiB dbuf
// LDS, 2 blocks/CU.  Only change vs R8 (best, 52.4 us): both operands now
// staged TWO tiles ahead (cover ~2 tiles ~3000+ cy >> L2-miss/L3 latency):
//   P0: read a[0..1](ks0,ks1) + b[0..1](ks0);             BAR; MFMA(ks0,mi0-1)
//   P1: read a[2..3](ks0,ks1);                            BAR; MFMA(ks0,mi2-3)
//   P2: read b[0..1](ks1); stage A(t+2)h0,h1 -> buf[p]    BAR; MFMA(ks1,mi0-1)
//       (A(t) dead after P1 — same region-death argument as R8)
//   P3: stage B(t+2)h0,h1 -> buf[p] (B(t) last read P2);
//       vmcnt(4); BAR; MFMA(ks1,mi2-3)
// Per-thread queue at P3-end: [A(t+1)x2, B(t+1)x2 | A(t+2)x2, B(t+2)x2]
// -> vmcnt(4) drains exactly tile t+1, leaves t+2 flying with 2-tile cover.
// Prologue stages tiles 0+1 (8 loads), vmcnt(4).  Tail: vmcnt(0) at t+2==NT.
// XOR-involution LDS swizzle (0 conflicts), XCD-chunked n-major swizzle.
// ---------------------------------------------------------------------------
__global__ __launch_bounds__(512, 4) void gemm_kernel(
    const us* __restrict__ A,   // causal bf16 [M_TOT][D_DIM]
    const us* __restrict__ Bw,  // W bf16 [D_DIM][D_DIM]
    const float* __restrict__ x,
    float* __restrict__ out) {
  __shared__ us smem_s[32768];   // 64 KiB: buf p at p*16384: A 8192us, B 8192us

  // nwg = 1024 = 8 XCDs x 128; n-major within XCD chunk.
  const int bid = blockIdx.x;
  const int xcd = bid & 7;
  const int q = bid >> 3;                   // 0..127
  const int m0 = (xcd * 16 + (q >> 3)) * 128;
  const int n0 = (q & 7) * 128;

  const int tid = threadIdx.x;
  const int lane = tid & 63;
  const int wave = tid >> 6;
  const int wr = wave >> 2;       // 0..1 (M half: 64 rows)
  const int wc = wave & 3;        // 0..3 (N quarter: 32 cols)
  const int lrow = lane & 15;
  const int ls   = lane >> 4;     // 0..3
  const int koff0 = ((0 + ls) ^ (lane & 7)) * 8;
  const int koff1 = ((4 + ls) ^ (lane & 7)) * 8;
  const int arow = (wr * 64 + lrow) * 64;   // + mi*1024 + koff
  const int brow = (wc * 32 + lrow) * 64;   // + nj*1024 + koff

  f32x4 acc[4][2];
#pragma unroll
  for (int i = 0; i < 4; ++i)
#pragma unroll
    for (int j = 0; j < 2; ++j) acc[i][j] = (f32x4)0.f;

  // Stage one half-tile (64 rows x 64 cols = 8 KB): 1 load/thread.
#define STAGE_HALF(SRC, rowbase, t, h, ldsbase)                                \
  {                                                                            \
    const int r = tid >> 3;               /* 0..63 */                          \
    const int slot = (tid & 7) ^ (r & 7);                                      \
    __builtin_amdgcn_global_load_lds(                                          \
        (const __attribute__((address_space(1))) void*)((SRC) +                \
            (size_t)((rowbase) + (h) * 64 + r) * D_DIM + (t) * 64 + slot * 8), \
        (__attribute__((address_space(3))) void*)(smem_s + (ldsbase) +         \
            (h) * 4096 + tid * 8),                                             \
        16, 0, 0);                                                             \
  }
#define BAR() __builtin_amdgcn_s_barrier()
#define MFMAQ(KS, MI0)                                                         \
  __builtin_amdgcn_s_setprio(1);                                               \
  _Pragma("unroll")                                                            \
  for (int mi = 0; mi < 2; ++mi)                                               \
    _Pragma("unroll")                                                          \
    for (int nj = 0; nj < 2; ++nj)                                             \
      acc[(MI0) + mi][nj] = __builtin_amdgcn_mfma_f32_16x16x32_bf16(           \
          a[(MI0) + mi][KS], b[nj][KS], acc[(MI0) + mi][nj], 0, 0, 0);         \
  __builtin_amdgcn_s_setprio(0)

  // LDS us-element bases: buf p: A = p*16384, B = p*16384 + 8192.
  // ---- prologue: tiles 0 and 1 fully staged; wait tile0 (vmcnt(4)) ----
  STAGE_HALF(A,  m0, 0, 0, 0);     STAGE_HALF(A,  m0, 0, 1, 0);
  STAGE_HALF(Bw, n0, 0, 0, 8192);  STAGE_HALF(Bw, n0, 0, 1, 8192);
  STAGE_HALF(A,  m0, 1, 0, 16384); STAGE_HALF(A,  m0, 1, 1, 16384);
  STAGE_HALF(Bw, n0, 1, 0, 24576); STAGE_HALF(Bw, n0, 1, 1, 24576);
  asm volatile("s_waitcnt vmcnt(4)" ::: "memory");   // tile0 resident
  BAR();

  bf16x8 a[4][2], b[2][2];

  for (int t = 0; t < NT; ++t) {
    const int p = t & 1;
    const int Ab = p * 16384;
    const int Bb = Ab + 8192;

    // ---- P0: a[0..1] both ks (4) + b[0..1] ks0 (2) ----
#pragma unroll
    for (int mi = 0; mi < 2; ++mi) {
      a[mi][0] = *(const bf16x8*)(smem_s + Ab + arow + mi * 1024 + koff0);
      a[mi][1] = *(const bf16x8*)(smem_s + Ab + arow + mi * 1024 + koff1);
    }
#pragma unroll
    for (int nj = 0; nj < 2; ++nj)
      b[nj][0] = *(const bf16x8*)(smem_s + Bb + brow + nj * 1024 + koff0);
    BAR();
    MFMAQ(0, 0);

    // ---- P1: a[2..3] both ks (4) ----
#pragma unroll
    for (int mi = 2; mi < 4; ++mi) {
      a[mi][0] = *(const bf16x8*)(smem_s + Ab + arow + mi * 1024 + koff0);
      a[mi][1] = *(const bf16x8*)(smem_s + Ab + arow + mi * 1024 + koff1);
    }
    BAR();
    MFMAQ(0, 2);

    // ---- P2: b[0..1] ks1 (2); stage A(t+2) h0+h1 into THIS buf ----
#pragma unroll
    for (int nj = 0; nj < 2; ++nj)
      b[nj][1] = *(const bf16x8*)(smem_s + Bb + brow + nj * 1024 + koff1);
    if (t + 2 < NT) {
      STAGE_HALF(A, m0, t + 2, 0, Ab);
      STAGE_HALF(A, m0, t + 2, 1, Ab);
    }
    BAR();
    MFMAQ(1, 0);

    // ---- P3: stage B(t+2) h0+h1 into THIS buf; counted wait; BAR; MFMA ----
    if (t + 2 < NT) {
      STAGE_HALF(Bw, n0, t + 2, 0, Bb);
      STAGE_HALF(Bw, n0, t + 2, 1, Bb);
      asm volatile("s_waitcnt vmcnt(4)" ::: "memory");  // tile t+1 resident
    } else if (t + 1 < NT) {
      asm volatile("s_waitcnt vmcnt(0)" ::: "memory");  // tail drain
    }
    BAR();
    MFMAQ(1, 2);
  }

  // ---- epilogue: out = x + acc.  C/D: col = lane&15, row = (lane>>4)*4+r ----
#pragma unroll
  for (int mi = 0; mi < 4; ++mi)
#pragma unroll
    for (int nj = 0; nj < 2; ++nj) {
      const int ocol = n0 + wc * 32 + nj * 16 + lrow;
      const int orow0 = m0 + wr * 64 + mi * 16 + ls * 4;
#pragma unroll
      for (int r = 0; r < 4; ++r) {
        const size_t idx = (size_t)(orow0 + r) * D_DIM + ocol;
        out[idx] = x[idx] + acc[mi][nj][r];
      }
    }
#undef STAGE_HALF
#undef BAR
#undef MFMAQ
}

extern "C" void kernel_launch(void* const* d_in, const int* in_sizes, int n_in,
                              void* d_out, int out_size, void* d_ws, size_t ws_size,
                              hipStream_t stream) {
  const float* x  = (const float*)d_in[0];
  const float* dp = (const float*)d_in[1];
  const float* W  = (const float*)d_in[2];
  float* out = (float*)d_out;

  us* causal = (us*)d_ws;
  us* Wb = (us*)((char*)d_ws + (size_t)M_TOT * D_DIM * 2);

  dim3 g_scan(D_DIM / 512, S_DIM / CHUNK, B_DIM);
  scan_kernel<<<g_scan, 256, 0, stream>>>(x, dp, causal);

  convw_kernel<<<(D_DIM * D_DIM) / (256 * 4), 256, 0, stream>>>(W, Wb);

  gemm_kernel<<<(M_TOT / 128) * (D_DIM / 128), 512, 0, stream>>>(
      causal, Wb, x, out);
}